// Round 4
// baseline (251.409 us; speedup 1.0000x reference)
//
#include <hip/hip_runtime.h>

// RMAC: x[64, 2048, 16, 16] f32 -> f[64, 14*2048] L2-normalized per batch row.
// Windows (H=W=16): l1: 16x16 -> 1 region (/256); l2: 10x10 stride 4 -> 2x2,
// rows/cols [0,10),[4,14) (/100); l3: 8x8 stride 3 -> 3x3, [0,8),[3,11),[6,14) (/64).
// Feature k (0..13) at out[b*FEAT + k*C + c].
//
// Round-7: depth-1 register prefetch in the pool loop. Previously each CU's
// waves entered the ~1100-cy compute phase in lockstep with ZERO loads in
// flight (periodic HBM bubble -> pool at ~76% of achievable BW vs fills' 87%).
// Now iteration s+1's 8 loads are issued before the LDS-write+compute of s;
// compiler emits counted vmcnt(8) so they stay in flight across compute.

constexpr int C    = 2048;
constexpr int NB   = 64;
constexpr int FEAT = 14 * C;       // 28672
constexpr float EPS = 1e-12f;

constexpr int IMG_S4  = 65;           // float4 stride per image in LDS (1040 B)
constexpr int WAVE_S4 = 8 * IMG_S4;   // 8 images staged per wave per iter
constexpr int NBLK    = (NB * C) / 256;  // 512 blocks = 2/CU x 256 CUs

__global__ __launch_bounds__(256, 2) void rmac_pool_kernel(
    const float4* __restrict__ x4, float* __restrict__ out,
    float* __restrict__ ws)
{
    __shared__ float4 stage[4 * WAVE_S4];   // 33280 B
    __shared__ float  otile[14][256];       // 14336 B
    __shared__ float  red[4];

    const int tid  = threadIdx.x;
    const int lane = tid & 63;
    const int w    = tid >> 6;
    const int t    = lane & 7;    // image within stage
    const int o    = lane >> 3;   // row pair 0..7 (rows 2o, 2o+1)

    const int blockImg = blockIdx.x * 256;
    float4* sw = stage + w * WAVE_S4;

    // prologue: issue s=0 loads
    float4 v[8];
    {
        const int imgBase = blockImg + w * 64;
        #pragma unroll
        for (int i = 0; i < 8; ++i)
            v[i] = x4[(size_t)(imgBase + i) * 64 + lane];
    }

    #pragma unroll 1
    for (int s = 0; s < 8; ++s) {
        // prefetch s+1 FIRST so its 8 loads are in flight across this
        // iteration's LDS write + compute (counted vmcnt keeps them pending)
        float4 vn[8];
        if (s < 7) {
            const int nextBase = blockImg + w * 64 + (s + 1) * 8;
            #pragma unroll
            for (int i = 0; i < 8; ++i)
                vn[i] = x4[(size_t)(nextBase + i) * 64 + lane];
        }

        // stage current iteration (waits only on the OLDER 8 loads)
        #pragma unroll
        for (int i = 0; i < 8; ++i)
            sw[i * IMG_S4 + lane] = v[i];
        // same-wave LDS RAW: in-order DS pipe + compiler lgkmcnt — no barrier needed

        float rs[14];
        #pragma unroll
        for (int k = 0; k < 14; ++k) rs[k] = 0.f;

        const float4* img = sw + t * IMG_S4 + o * 8;   // rows 2o, 2o+1
        #pragma unroll
        for (int r = 0; r < 2; ++r) {
            float4 a0 = img[r*4+0], a1 = img[r*4+1], a2 = img[r*4+2], a3 = img[r*4+3];
            float vv[16] = {a0.x,a0.y,a0.z,a0.w, a1.x,a1.y,a1.z,a1.w,
                            a2.x,a2.y,a2.z,a2.w, a3.x,a3.y,a3.z,a3.w};
            float pref[17]; pref[0] = 0.f;
            #pragma unroll
            for (int k2 = 0; k2 < 16; ++k2) pref[k2+1] = pref[k2] + vv[k2];

            const float full = pref[16];
            const float c20  = pref[10];             // cols [0,10)
            const float c21  = pref[14] - pref[4];   // cols [4,14)
            const float c30  = pref[8];              // cols [0,8)
            const float c31  = pref[11] - pref[3];   // cols [3,11)
            const float c32  = pref[14] - pref[6];   // cols [6,14)

            const int y = o * 2 + r;                 // lane-dependent -> predicated adds
            bool m;
            rs[0] += full;
            m = (y < 10);          rs[1]  += m ? c20 : 0.f; rs[2]  += m ? c21 : 0.f;
            m = (y >= 4 && y < 14);rs[3]  += m ? c20 : 0.f; rs[4]  += m ? c21 : 0.f;
            m = (y < 8);           rs[5]  += m ? c30 : 0.f; rs[6]  += m ? c31 : 0.f; rs[7]  += m ? c32 : 0.f;
            m = (y >= 3 && y < 11);rs[8]  += m ? c30 : 0.f; rs[9]  += m ? c31 : 0.f; rs[10] += m ? c32 : 0.f;
            m = (y >= 6 && y < 14);rs[11] += m ? c30 : 0.f; rs[12] += m ? c31 : 0.f; rs[13] += m ? c32 : 0.f;
        }

        // combine the 8 row-pairs (lanes t, t+8, ..., t+56)
        #pragma unroll
        for (int k = 0; k < 14; ++k) {
            rs[k] += __shfl_xor(rs[k], 8, 64);
            rs[k] += __shfl_xor(rs[k], 16, 64);
            rs[k] += __shfl_xor(rs[k], 32, 64);
        }

        const int col = w * 64 + s * 8 + t;
        #pragma unroll
        for (int k = 0; k < 14; ++k) {
            const float sc = (k == 0) ? (1.f/256.f) : (k < 5 ? (1.f/100.f) : (1.f/64.f));
            if ((k & 7) == o) otile[k][col] = rs[k] * sc;   // o-groups split the 14 writes
        }

        #pragma unroll
        for (int i = 0; i < 8; ++i) v[i] = vn[i];   // rotate prefetch buffer
    }
    __syncthreads();

    // coalesced feature stores (block covers 256 consecutive c of one b),
    // fused with the block's sum-of-squares partial
    const int img = blockImg + tid;
    const int b   = img >> 11;
    const int c   = img & (C - 1);
    float ssl = 0.f;
    #pragma unroll
    for (int k = 0; k < 14; ++k) {
        const float vv = otile[k][tid];
        out[(size_t)b * FEAT + (size_t)k * C + c] = vv;
        ssl += vv * vv;
    }
    #pragma unroll
    for (int off = 32; off; off >>= 1) ssl += __shfl_down(ssl, off, 64);
    if ((tid & 63) == 0) red[tid >> 6] = ssl;
    __syncthreads();
    if (tid == 0 && ws != nullptr)
        ws[blockIdx.x] = red[0] + red[1] + red[2] + red[3];
}

// 512 blocks (8 per batch row) — full-chip BW for the scale pass.
// Row total ss = sum of the row's 8 block partials from ws (kernel-boundary
// on the stream guarantees visibility; L2-hot broadcast reads).
__global__ __launch_bounds__(128) void rmac_scale_kernel(
    float* __restrict__ out, const float* __restrict__ ws)
{
    const int g     = blockIdx.x;        // 0..511
    const int b     = g >> 3;
    const int chunk = g & 7;

    float tot = 0.f;
    #pragma unroll
    for (int j = 0; j < 8; ++j) tot += ws[(b << 3) + j];
    const float s = 1.f / fmaxf(sqrtf(tot), EPS);

    // 7168 float4 per row; this block owns 896 of them; 128 threads x 7 each.
    float4* row = reinterpret_cast<float4*>(out + (size_t)b * FEAT) + chunk * 896;
    const int tid = threadIdx.x;
    #pragma unroll
    for (int j = 0; j < 7; ++j) {
        float4 v = row[tid + j * 128];
        v.x *= s; v.y *= s; v.z *= s; v.w *= s;
        row[tid + j * 128] = v;
    }
}

// Fallback (ws unavailable): recompute row ss, 64 blocks x 1024 threads.
__global__ __launch_bounds__(1024) void rmac_norm_kernel(float* __restrict__ out)
{
    const int b   = blockIdx.x;
    const int tid = threadIdx.x;
    float4* row = reinterpret_cast<float4*>(out + (size_t)b * FEAT);  // 7168 float4

    float4 v[7];
    float ss = 0.f;
    #pragma unroll
    for (int j = 0; j < 7; ++j) {
        v[j] = row[tid + j * 1024];
        ss += v[j].x*v[j].x + v[j].y*v[j].y + v[j].z*v[j].z + v[j].w*v[j].w;
    }

    #pragma unroll
    for (int off = 32; off; off >>= 1) ss += __shfl_down(ss, off, 64);
    __shared__ float red[16];
    const int lane = tid & 63, w = tid >> 6;
    if (lane == 0) red[w] = ss;
    __syncthreads();
    float tot = 0.f;
    #pragma unroll
    for (int i = 0; i < 16; ++i) tot += red[i];   // broadcast reads, no conflicts

    const float s = 1.f / fmaxf(sqrtf(tot), EPS);
    #pragma unroll
    for (int j = 0; j < 7; ++j) {
        v[j].x *= s; v[j].y *= s; v[j].z *= s; v[j].w *= s;
        row[tid + j * 1024] = v[j];
    }
}

extern "C" void kernel_launch(void* const* d_in, const int* in_sizes, int n_in,
                              void* d_out, int out_size, void* d_ws, size_t ws_size,
                              hipStream_t stream)
{
    const float4* x4 = (const float4*)d_in[0];
    float* out       = (float*)d_out;
    float* ws        = (float*)d_ws;

    const bool ws_ok = (ws != nullptr) && (ws_size >= NBLK * sizeof(float));

    rmac_pool_kernel<<<NBLK, 256, 0, stream>>>(x4, out, ws_ok ? ws : nullptr);
    if (ws_ok)
        rmac_scale_kernel<<<NBLK, 128, 0, stream>>>(out, ws);
    else
        rmac_norm_kernel<<<NB, 1024, 0, stream>>>(out);
}

// Round 7
// 216.102 us; speedup vs baseline: 1.1634x; 1.1634x over previous
//
#include <hip/hip_runtime.h>

// RMAC: x[64, 2048, 16, 16] f32 -> f[64, 14*2048] L2-normalized per batch row.
// Windows (H=W=16): l1: 16x16 -> 1 region (/256); l2: 10x10 stride 4 -> 2x2,
// rows/cols [0,10),[4,14) (/100); l3: 8x8 stride 3 -> 3x3, [0,8),[3,11),[6,14) (/64).
// Feature k (0..13) at out[b*FEAT + k*C + c].
//
// Round-10: second resubmit (bench infra failed at container-acquire level in
// rounds 8/9; same error mode as round 2, which passed unchanged on retry).
// Depth-1 prefetch without scratch: explicit va/vb double-buffer, statically
// selected per iteration in straight-line code, zero conditional assignment,
// zero rotation. LDS-write of iter s waits counted vmcnt while iter s+1's 8
// loads stay in flight across compute (fixes the lockstep-compute HBM bubble;
// avoids round-7's rolled-loop conditional-def scratch spill).

constexpr int C    = 2048;
constexpr int NB   = 64;
constexpr int FEAT = 14 * C;       // 28672
constexpr float EPS = 1e-12f;

constexpr int IMG_S4  = 65;           // float4 stride per image in LDS (1040 B)
constexpr int WAVE_S4 = 8 * IMG_S4;   // 8 images staged per wave per iter
constexpr int NBLK    = (NB * C) / 256;  // 512 blocks = 2/CU x 256 CUs

__global__ __launch_bounds__(256, 2) void rmac_pool_kernel(
    const float4* __restrict__ x4, float* __restrict__ out,
    float* __restrict__ ws)
{
    __shared__ float4 stage[4 * WAVE_S4];   // 33280 B
    __shared__ float  otile[14][256];       // 14336 B
    __shared__ float  red[4];

    const int tid  = threadIdx.x;
    const int lane = tid & 63;
    const int w    = tid >> 6;
    const int t    = lane & 7;    // image within stage
    const int o    = lane >> 3;   // row pair 0..7 (rows 2o, 2o+1)

    const int blockImg = blockIdx.x * 256;
    float4* sw = stage + w * WAVE_S4;

    // 8 perfectly-coalesced 1 KiB loads (one whole image per instruction)
    auto load8 = [&](float4 (&dst)[8], const int s) {
        const int imgBase = blockImg + w * 64 + s * 8;
        #pragma unroll
        for (int i = 0; i < 8; ++i)
            dst[i] = x4[(size_t)(imgBase + i) * 64 + lane];
    };

    auto iter = [&](const float4 (&vv8)[8], const int s) {
        // stage (waits only on the OLDER 8 loads -> counted vmcnt)
        #pragma unroll
        for (int i = 0; i < 8; ++i)
            sw[i * IMG_S4 + lane] = vv8[i];
        // same-wave LDS RAW: in-order DS pipe + compiler lgkmcnt — no barrier

        float rs[14];
        #pragma unroll
        for (int k = 0; k < 14; ++k) rs[k] = 0.f;

        const float4* img = sw + t * IMG_S4 + o * 8;   // rows 2o, 2o+1
        #pragma unroll
        for (int r = 0; r < 2; ++r) {
            float4 a0 = img[r*4+0], a1 = img[r*4+1], a2 = img[r*4+2], a3 = img[r*4+3];
            float vv[16] = {a0.x,a0.y,a0.z,a0.w, a1.x,a1.y,a1.z,a1.w,
                            a2.x,a2.y,a2.z,a2.w, a3.x,a3.y,a3.z,a3.w};
            float pref[17]; pref[0] = 0.f;
            #pragma unroll
            for (int k2 = 0; k2 < 16; ++k2) pref[k2+1] = pref[k2] + vv[k2];

            const float full = pref[16];
            const float c20  = pref[10];             // cols [0,10)
            const float c21  = pref[14] - pref[4];   // cols [4,14)
            const float c30  = pref[8];              // cols [0,8)
            const float c31  = pref[11] - pref[3];   // cols [3,11)
            const float c32  = pref[14] - pref[6];   // cols [6,14)

            const int y = o * 2 + r;                 // lane-dependent -> predicated adds
            bool m;
            rs[0] += full;
            m = (y < 10);          rs[1]  += m ? c20 : 0.f; rs[2]  += m ? c21 : 0.f;
            m = (y >= 4 && y < 14);rs[3]  += m ? c20 : 0.f; rs[4]  += m ? c21 : 0.f;
            m = (y < 8);           rs[5]  += m ? c30 : 0.f; rs[6]  += m ? c31 : 0.f; rs[7]  += m ? c32 : 0.f;
            m = (y >= 3 && y < 11);rs[8]  += m ? c30 : 0.f; rs[9]  += m ? c31 : 0.f; rs[10] += m ? c32 : 0.f;
            m = (y >= 6 && y < 14);rs[11] += m ? c30 : 0.f; rs[12] += m ? c31 : 0.f; rs[13] += m ? c32 : 0.f;
        }

        // combine the 8 row-pairs (lanes t, t+8, ..., t+56)
        #pragma unroll
        for (int k = 0; k < 14; ++k) {
            rs[k] += __shfl_xor(rs[k], 8, 64);
            rs[k] += __shfl_xor(rs[k], 16, 64);
            rs[k] += __shfl_xor(rs[k], 32, 64);
        }

        const int col = w * 64 + s * 8 + t;
        #pragma unroll
        for (int k = 0; k < 14; ++k) {
            const float sc = (k == 0) ? (1.f/256.f) : (k < 5 ? (1.f/100.f) : (1.f/64.f));
            if ((k & 7) == o) otile[k][col] = rs[k] * sc;   // o-groups split the 14 writes
        }
    };

    // software pipeline, depth 1, all buffer choices static (no scratch)
    float4 va[8], vb[8];
    load8(va, 0);
    load8(vb, 1);
    iter(va, 0);  load8(va, 2);
    iter(vb, 1);  load8(vb, 3);
    iter(va, 2);  load8(va, 4);
    iter(vb, 3);  load8(vb, 5);
    iter(va, 4);  load8(va, 6);
    iter(vb, 5);  load8(vb, 7);
    iter(va, 6);
    iter(vb, 7);

    __syncthreads();

    // coalesced feature stores (block covers 256 consecutive c of one b),
    // fused with the block's sum-of-squares partial
    const int img = blockImg + tid;
    const int b   = img >> 11;
    const int c   = img & (C - 1);
    float ssl = 0.f;
    #pragma unroll
    for (int k = 0; k < 14; ++k) {
        const float vv = otile[k][tid];
        out[(size_t)b * FEAT + (size_t)k * C + c] = vv;
        ssl += vv * vv;
    }
    #pragma unroll
    for (int off = 32; off; off >>= 1) ssl += __shfl_down(ssl, off, 64);
    if ((tid & 63) == 0) red[tid >> 6] = ssl;
    __syncthreads();
    if (tid == 0 && ws != nullptr)
        ws[blockIdx.x] = red[0] + red[1] + red[2] + red[3];
}

// 512 blocks (8 per batch row) — full-chip BW for the scale pass.
// Row total ss = sum of the row's 8 block partials from ws (kernel-boundary
// on the stream guarantees visibility; L2-hot broadcast reads).
__global__ __launch_bounds__(128) void rmac_scale_kernel(
    float* __restrict__ out, const float* __restrict__ ws)
{
    const int g     = blockIdx.x;        // 0..511
    const int b     = g >> 3;
    const int chunk = g & 7;

    float tot = 0.f;
    #pragma unroll
    for (int j = 0; j < 8; ++j) tot += ws[(b << 3) + j];
    const float s = 1.f / fmaxf(sqrtf(tot), EPS);

    // 7168 float4 per row; this block owns 896 of them; 128 threads x 7 each.
    float4* row = reinterpret_cast<float4*>(out + (size_t)b * FEAT) + chunk * 896;
    const int tid = threadIdx.x;
    #pragma unroll
    for (int j = 0; j < 7; ++j) {
        float4 v = row[tid + j * 128];
        v.x *= s; v.y *= s; v.z *= s; v.w *= s;
        row[tid + j * 128] = v;
    }
}

// Fallback (ws unavailable): recompute row ss, 64 blocks x 1024 threads.
__global__ __launch_bounds__(1024) void rmac_norm_kernel(float* __restrict__ out)
{
    const int b   = blockIdx.x;
    const int tid = threadIdx.x;
    float4* row = reinterpret_cast<float4*>(out + (size_t)b * FEAT);  // 7168 float4

    float4 v[7];
    float ss = 0.f;
    #pragma unroll
    for (int j = 0; j < 7; ++j) {
        v[j] = row[tid + j * 1024];
        ss += v[j].x*v[j].x + v[j].y*v[j].y + v[j].z*v[j].z + v[j].w*v[j].w;
    }

    #pragma unroll
    for (int off = 32; off; off >>= 1) ss += __shfl_down(ss, off, 64);
    __shared__ float red[16];
    const int lane = tid & 63, w = tid >> 6;
    if (lane == 0) red[w] = ss;
    __syncthreads();
    float tot = 0.f;
    #pragma unroll
    for (int i = 0; i < 16; ++i) tot += red[i];   // broadcast reads, no conflicts

    const float s = 1.f / fmaxf(sqrtf(tot), EPS);
    #pragma unroll
    for (int j = 0; j < 7; ++j) {
        v[j].x *= s; v[j].y *= s; v[j].z *= s; v[j].w *= s;
        row[tid + j * 1024] = v[j];
    }
}

extern "C" void kernel_launch(void* const* d_in, const int* in_sizes, int n_in,
                              void* d_out, int out_size, void* d_ws, size_t ws_size,
                              hipStream_t stream)
{
    const float4* x4 = (const float4*)d_in[0];
    float* out       = (float*)d_out;
    float* ws        = (float*)d_ws;

    const bool ws_ok = (ws != nullptr) && (ws_size >= NBLK * sizeof(float));

    rmac_pool_kernel<<<NBLK, 256, 0, stream>>>(x4, out, ws_ok ? ws : nullptr);
    if (ws_ok)
        rmac_scale_kernel<<<NBLK, 128, 0, stream>>>(out, ws);
    else
        rmac_norm_kernel<<<NB, 1024, 0, stream>>>(out);
}

// Round 8
// 196.678 us; speedup vs baseline: 1.2783x; 1.0988x over previous
//
#include <hip/hip_runtime.h>

// RMAC: x[64, 2048, 16, 16] f32 -> f[64, 14*2048] L2-normalized per batch row.
// Windows (H=W=16): l1: 16x16 -> 1 region (/256); l2: 10x10 stride 4 -> 2x2,
// rows/cols [0,10),[4,14) (/100); l3: 8x8 stride 3 -> 3x3, [0,8),[3,11),[6,14) (/64).
// Feature k (0..13) at out[b*FEAT + k*C + c].
//
// Round-11: depth-1 prefetch, third implementation. Round-4 spilled via a
// conditionally-defined rotated array; round-7 spilled via arrays passed BY
// REFERENCE into lambdas (address-taken -> local memory; VGPR stayed 68,
// WRITE_SIZE 134 MB). This version uses ONLY named scalar float4s (A0..A7,
// B0..B7) with macros expanding to direct uses — cannot be address-taken,
// guaranteed register-resident (~130 VGPR, fine at 3 waves/SIMD).
// Schedule per step: STAGE(X) [waits counted vmcnt for X's loads only],
// LOAD(X, s+2) [8 new loads in flight], compute(s) [overlapped with loads].

constexpr int C    = 2048;
constexpr int NB   = 64;
constexpr int FEAT = 14 * C;       // 28672
constexpr float EPS = 1e-12f;

constexpr int IMG_S4  = 65;           // float4 stride per image in LDS (1040 B)
constexpr int WAVE_S4 = 8 * IMG_S4;   // 8 images staged per wave per iter
constexpr int NBLK    = (NB * C) / 256;  // 512 blocks = 2/CU x 256 CUs

#define LOAD8(n0,n1,n2,n3,n4,n5,n6,n7, S)                                   \
    {                                                                       \
        const float4* p = x4 + (size_t)(blockImg + w * 64 + (S) * 8) * 64 + lane; \
        n0 = p[0*64]; n1 = p[1*64]; n2 = p[2*64]; n3 = p[3*64];             \
        n4 = p[4*64]; n5 = p[5*64]; n6 = p[6*64]; n7 = p[7*64];             \
    }

#define STAGE8(n0,n1,n2,n3,n4,n5,n6,n7)                                     \
    {                                                                       \
        sw[0*IMG_S4+lane]=n0; sw[1*IMG_S4+lane]=n1;                         \
        sw[2*IMG_S4+lane]=n2; sw[3*IMG_S4+lane]=n3;                         \
        sw[4*IMG_S4+lane]=n4; sw[5*IMG_S4+lane]=n5;                         \
        sw[6*IMG_S4+lane]=n6; sw[7*IMG_S4+lane]=n7;                         \
    }

__global__ __launch_bounds__(256, 2) void rmac_pool_kernel(
    const float4* __restrict__ x4, float* __restrict__ out,
    float* __restrict__ ws)
{
    __shared__ float4 stage[4 * WAVE_S4];   // 33280 B
    __shared__ float  otile[14][256];       // 14336 B
    __shared__ float  red[4];

    const int tid  = threadIdx.x;
    const int lane = tid & 63;
    const int w    = tid >> 6;
    const int t    = lane & 7;    // image within stage
    const int o    = lane >> 3;   // row pair 0..7 (rows 2o, 2o+1)

    const int blockImg = blockIdx.x * 256;
    float4* sw = stage + w * WAVE_S4;

    // compute on the currently-staged 8 images (reads LDS only; round-3-proven)
    auto compute = [&](const int s) {
        float rs[14];
        #pragma unroll
        for (int k = 0; k < 14; ++k) rs[k] = 0.f;

        const float4* img = sw + t * IMG_S4 + o * 8;   // rows 2o, 2o+1
        #pragma unroll
        for (int r = 0; r < 2; ++r) {
            float4 a0 = img[r*4+0], a1 = img[r*4+1], a2 = img[r*4+2], a3 = img[r*4+3];
            float vv[16] = {a0.x,a0.y,a0.z,a0.w, a1.x,a1.y,a1.z,a1.w,
                            a2.x,a2.y,a2.z,a2.w, a3.x,a3.y,a3.z,a3.w};
            float pref[17]; pref[0] = 0.f;
            #pragma unroll
            for (int k2 = 0; k2 < 16; ++k2) pref[k2+1] = pref[k2] + vv[k2];

            const float full = pref[16];
            const float c20  = pref[10];             // cols [0,10)
            const float c21  = pref[14] - pref[4];   // cols [4,14)
            const float c30  = pref[8];              // cols [0,8)
            const float c31  = pref[11] - pref[3];   // cols [3,11)
            const float c32  = pref[14] - pref[6];   // cols [6,14)

            const int y = o * 2 + r;                 // lane-dependent -> predicated adds
            bool m;
            rs[0] += full;
            m = (y < 10);          rs[1]  += m ? c20 : 0.f; rs[2]  += m ? c21 : 0.f;
            m = (y >= 4 && y < 14);rs[3]  += m ? c20 : 0.f; rs[4]  += m ? c21 : 0.f;
            m = (y < 8);           rs[5]  += m ? c30 : 0.f; rs[6]  += m ? c31 : 0.f; rs[7]  += m ? c32 : 0.f;
            m = (y >= 3 && y < 11);rs[8]  += m ? c30 : 0.f; rs[9]  += m ? c31 : 0.f; rs[10] += m ? c32 : 0.f;
            m = (y >= 6 && y < 14);rs[11] += m ? c30 : 0.f; rs[12] += m ? c31 : 0.f; rs[13] += m ? c32 : 0.f;
        }

        // combine the 8 row-pairs (lanes t, t+8, ..., t+56)
        #pragma unroll
        for (int k = 0; k < 14; ++k) {
            rs[k] += __shfl_xor(rs[k], 8, 64);
            rs[k] += __shfl_xor(rs[k], 16, 64);
            rs[k] += __shfl_xor(rs[k], 32, 64);
        }

        const int col = w * 64 + s * 8 + t;
        #pragma unroll
        for (int k = 0; k < 14; ++k) {
            const float sc = (k == 0) ? (1.f/256.f) : (k < 5 ? (1.f/100.f) : (1.f/64.f));
            if ((k & 7) == o) otile[k][col] = rs[k] * sc;   // o-groups split the 14 writes
        }
    };

    // depth-1 software pipeline on named scalars (no arrays in staging path)
    float4 A0,A1,A2,A3,A4,A5,A6,A7;
    float4 B0,B1,B2,B3,B4,B5,B6,B7;

    LOAD8(A0,A1,A2,A3,A4,A5,A6,A7, 0);
    LOAD8(B0,B1,B2,B3,B4,B5,B6,B7, 1);

    STAGE8(A0,A1,A2,A3,A4,A5,A6,A7);  LOAD8(A0,A1,A2,A3,A4,A5,A6,A7, 2);  compute(0);
    STAGE8(B0,B1,B2,B3,B4,B5,B6,B7);  LOAD8(B0,B1,B2,B3,B4,B5,B6,B7, 3);  compute(1);
    STAGE8(A0,A1,A2,A3,A4,A5,A6,A7);  LOAD8(A0,A1,A2,A3,A4,A5,A6,A7, 4);  compute(2);
    STAGE8(B0,B1,B2,B3,B4,B5,B6,B7);  LOAD8(B0,B1,B2,B3,B4,B5,B6,B7, 5);  compute(3);
    STAGE8(A0,A1,A2,A3,A4,A5,A6,A7);  LOAD8(A0,A1,A2,A3,A4,A5,A6,A7, 6);  compute(4);
    STAGE8(B0,B1,B2,B3,B4,B5,B6,B7);  LOAD8(B0,B1,B2,B3,B4,B5,B6,B7, 7);  compute(5);
    STAGE8(A0,A1,A2,A3,A4,A5,A6,A7);  compute(6);
    STAGE8(B0,B1,B2,B3,B4,B5,B6,B7);  compute(7);

    __syncthreads();

    // coalesced feature stores (block covers 256 consecutive c of one b),
    // fused with the block's sum-of-squares partial
    const int img = blockImg + tid;
    const int b   = img >> 11;
    const int c   = img & (C - 1);
    float ssl = 0.f;
    #pragma unroll
    for (int k = 0; k < 14; ++k) {
        const float vv = otile[k][tid];
        out[(size_t)b * FEAT + (size_t)k * C + c] = vv;
        ssl += vv * vv;
    }
    #pragma unroll
    for (int off = 32; off; off >>= 1) ssl += __shfl_down(ssl, off, 64);
    if ((tid & 63) == 0) red[tid >> 6] = ssl;
    __syncthreads();
    if (tid == 0 && ws != nullptr)
        ws[blockIdx.x] = red[0] + red[1] + red[2] + red[3];
}

// 512 blocks (8 per batch row) — full-chip BW for the scale pass.
// Row total ss = sum of the row's 8 block partials from ws (kernel-boundary
// on the stream guarantees visibility; L2-hot broadcast reads).
__global__ __launch_bounds__(128) void rmac_scale_kernel(
    float* __restrict__ out, const float* __restrict__ ws)
{
    const int g     = blockIdx.x;        // 0..511
    const int b     = g >> 3;
    const int chunk = g & 7;

    float tot = 0.f;
    #pragma unroll
    for (int j = 0; j < 8; ++j) tot += ws[(b << 3) + j];
    const float s = 1.f / fmaxf(sqrtf(tot), EPS);

    // 7168 float4 per row; this block owns 896 of them; 128 threads x 7 each.
    float4* row = reinterpret_cast<float4*>(out + (size_t)b * FEAT) + chunk * 896;
    const int tid = threadIdx.x;
    #pragma unroll
    for (int j = 0; j < 7; ++j) {
        float4 v = row[tid + j * 128];
        v.x *= s; v.y *= s; v.z *= s; v.w *= s;
        row[tid + j * 128] = v;
    }
}

// Fallback (ws unavailable): recompute row ss, 64 blocks x 1024 threads.
__global__ __launch_bounds__(1024) void rmac_norm_kernel(float* __restrict__ out)
{
    const int b   = blockIdx.x;
    const int tid = threadIdx.x;
    float4* row = reinterpret_cast<float4*>(out + (size_t)b * FEAT);  // 7168 float4

    float4 v[7];
    float ss = 0.f;
    #pragma unroll
    for (int j = 0; j < 7; ++j) {
        v[j] = row[tid + j * 1024];
        ss += v[j].x*v[j].x + v[j].y*v[j].y + v[j].z*v[j].z + v[j].w*v[j].w;
    }

    #pragma unroll
    for (int off = 32; off; off >>= 1) ss += __shfl_down(ss, off, 64);
    __shared__ float red[16];
    const int lane = tid & 63, w = tid >> 6;
    if (lane == 0) red[w] = ss;
    __syncthreads();
    float tot = 0.f;
    #pragma unroll
    for (int i = 0; i < 16; ++i) tot += red[i];   // broadcast reads, no conflicts

    const float s = 1.f / fmaxf(sqrtf(tot), EPS);
    #pragma unroll
    for (int j = 0; j < 7; ++j) {
        v[j].x *= s; v[j].y *= s; v[j].z *= s; v[j].w *= s;
        row[tid + j * 1024] = v[j];
    }
}

extern "C" void kernel_launch(void* const* d_in, const int* in_sizes, int n_in,
                              void* d_out, int out_size, void* d_ws, size_t ws_size,
                              hipStream_t stream)
{
    const float4* x4 = (const float4*)d_in[0];
    float* out       = (float*)d_out;
    float* ws        = (float*)d_ws;

    const bool ws_ok = (ws != nullptr) && (ws_size >= NBLK * sizeof(float));

    rmac_pool_kernel<<<NBLK, 256, 0, stream>>>(x4, out, ws_ok ? ws : nullptr);
    if (ws_ok)
        rmac_scale_kernel<<<NBLK, 128, 0, stream>>>(out, ws);
    else
        rmac_norm_kernel<<<NB, 1024, 0, stream>>>(out);
}